// Round 1
// baseline (492.311 us; speedup 1.0000x reference)
//
#include <hip/hip_runtime.h>

static __device__ __forceinline__ float silu_f(float v) {
    return v / (1.0f + __expf(-v));
}

extern "C" __global__ void k_deg(const int* __restrict__ dst, int* __restrict__ deg, int E) {
    int e = blockIdx.x * 256 + threadIdx.x;
    if (e < E) atomicAdd(&deg[dst[e]], 1);
}

extern "C" __global__ void k_dinv(const int* __restrict__ deg, float* __restrict__ dinv, int n) {
    int i = blockIdx.x * 256 + threadIdx.x;
    if (i < n) dinv[i] = rsqrtf((float)(deg[i] + 1));   // +1 = self loop; deg>=1 always
}

extern "C" __global__ void k_scan_partial(const int* __restrict__ deg, int* __restrict__ bsum, int n) {
    int base = blockIdx.x * 1024;
    int s = 0;
    for (int i = threadIdx.x; i < 1024; i += 256) {
        int idx = base + i;
        s += (idx < n) ? deg[idx] : 0;
    }
    for (int off = 1; off < 64; off <<= 1) s += __shfl_xor(s, off, 64);
    __shared__ int wsum[4];
    if ((threadIdx.x & 63) == 0) wsum[threadIdx.x >> 6] = s;
    __syncthreads();
    if (threadIdx.x == 0) bsum[blockIdx.x] = wsum[0] + wsum[1] + wsum[2] + wsum[3];
}

extern "C" __global__ void k_scan_bsum(int* __restrict__ bsum, int nb) {
    if (threadIdx.x == 0 && blockIdx.x == 0) {
        int run = 0;
        for (int i = 0; i < nb; i++) { int v = bsum[i]; bsum[i] = run; run += v; }
    }
}

extern "C" __global__ void k_scan_write(const int* __restrict__ deg, const int* __restrict__ bsum,
                                        int* __restrict__ rowstart, int n) {
    int t = threadIdx.x;
    int base = blockIdx.x * 1024;
    int v[4], loc[4];
    int s = 0;
    #pragma unroll
    for (int i = 0; i < 4; i++) {
        int idx = base + t * 4 + i;
        v[i] = (idx < n) ? deg[idx] : 0;
        loc[i] = s; s += v[i];
    }
    __shared__ int sc[256];
    sc[t] = s;
    __syncthreads();
    int mine = s;
    for (int off = 1; off < 256; off <<= 1) {
        int add = (t >= off) ? sc[t - off] : 0;
        __syncthreads();
        sc[t] += add;
        __syncthreads();
    }
    int excl = sc[t] - mine + bsum[blockIdx.x];
    #pragma unroll
    for (int i = 0; i < 4; i++) {
        int idx = base + t * 4 + i;
        if (idx < n) rowstart[idx] = excl + loc[i];
    }
}

extern "C" __global__ void k_fill(const int* __restrict__ src, const int* __restrict__ dst,
                                  const int* __restrict__ rowstart, int* __restrict__ cursor,
                                  int* __restrict__ csr, int E) {
    int e = blockIdx.x * 256 + threadIdx.x;
    if (e >= E) return;
    int d = dst[e];
    int pos = atomicAdd(&cursor[d], 1);
    csr[rowstart[d] + pos] = src[e];
}

// h0s = (x @ W1) * dinv[row]   (prescaled for symmetric norm)
// r1  = silu(x @ Wr1 + br1)
extern "C" __global__ __launch_bounds__(256) void k_gemm1(
    const float* __restrict__ x, const float* __restrict__ W1, const float* __restrict__ Wr1,
    const float* __restrict__ br1, const float* __restrict__ dinv,
    float* __restrict__ h0s, float* __restrict__ r1, int n)
{
    __shared__ float xs[64][33];     // +1 pad: conflict-free row reads
    __shared__ float wsm[32][128];   // combined [W1 | Wr1] K-chunk
    int t = threadIdx.x;
    int r0 = blockIdx.x * 64;
    int rg = t >> 4, cg = t & 15;    // thread tile: 4 rows x 8 cols (cols strided by 16)
    float acc[4][8];
    #pragma unroll
    for (int i = 0; i < 4; i++)
        #pragma unroll
        for (int j = 0; j < 8; j++) acc[i][j] = 0.0f;

    int lr = t >> 2;            // 0..63: x-load row
    int lkb = (t & 3) * 8;      // k sub-offset
    int wc = t & 127;           // W-load col
    int wk0 = t >> 7;           // 0/1

    for (int kk = 0; kk < 128; kk += 32) {
        {
            int grow = r0 + lr;
            float4 v0 = make_float4(0.f,0.f,0.f,0.f), v1 = v0;
            if (grow < n) {
                const float4* p = (const float4*)&x[grow * 128 + kk + lkb];
                v0 = p[0]; v1 = p[1];
            }
            xs[lr][lkb+0] = v0.x; xs[lr][lkb+1] = v0.y; xs[lr][lkb+2] = v0.z; xs[lr][lkb+3] = v0.w;
            xs[lr][lkb+4] = v1.x; xs[lr][lkb+5] = v1.y; xs[lr][lkb+6] = v1.z; xs[lr][lkb+7] = v1.w;
        }
        #pragma unroll
        for (int i = 0; i < 16; i++) {
            int k = i * 2 + wk0;
            float v = (wc < 64) ? W1[(kk + k) * 64 + wc] : Wr1[(kk + k) * 64 + (wc - 64)];
            wsm[k][wc] = v;
        }
        __syncthreads();
        #pragma unroll
        for (int k = 0; k < 32; k++) {
            float xv[4], wv[8];
            #pragma unroll
            for (int i = 0; i < 4; i++) xv[i] = xs[rg * 4 + i][k];
            #pragma unroll
            for (int j = 0; j < 8; j++) wv[j] = wsm[k][cg + 16 * j];
            #pragma unroll
            for (int i = 0; i < 4; i++)
                #pragma unroll
                for (int j = 0; j < 8; j++) acc[i][j] += xv[i] * wv[j];
        }
        __syncthreads();
    }
    #pragma unroll
    for (int i = 0; i < 4; i++) {
        int row = r0 + rg * 4 + i;
        if (row >= n) continue;
        float dv = dinv[row];
        #pragma unroll
        for (int j = 0; j < 4; j++) {
            int c = cg + 16 * j;
            h0s[row * 64 + c] = acc[i][j] * dv;
        }
        #pragma unroll
        for (int j = 4; j < 8; j++) {
            int c = cg + 16 * (j - 4);
            float v = acc[i][j] + br1[c];
            r1[row * 64 + c] = silu_f(v);
        }
    }
}

// h = silu(dinv[dst]*(sum_src h0s + h0s[dst]) + b1) + r1*alpha1 ; written in place over r1
extern "C" __global__ __launch_bounds__(256) void k_agg1(
    const float* __restrict__ h0s, const int* __restrict__ rowstart, const int* __restrict__ deg,
    const int* __restrict__ csr, const float* __restrict__ dinv, const float* __restrict__ b1,
    const float* __restrict__ alpha1, float* __restrict__ r1h, int n)
{
    int wave = threadIdx.x >> 6, lane = threadIdx.x & 63;
    int node = blockIdx.x * 4 + wave;
    if (node >= n) return;
    int rs = rowstart[node];
    int cnt = deg[node];
    float acc = h0s[node * 64 + lane];       // self loop
    int i = 0;
    for (; i + 4 <= cnt; i += 4) {           // 4 gathers in flight
        int s0 = csr[rs + i], s1 = csr[rs + i + 1], s2 = csr[rs + i + 2], s3 = csr[rs + i + 3];
        float a0 = h0s[s0 * 64 + lane], a1 = h0s[s1 * 64 + lane];
        float a2 = h0s[s2 * 64 + lane], a3 = h0s[s3 * 64 + lane];
        acc += (a0 + a1) + (a2 + a3);
    }
    for (; i < cnt; i++) acc += h0s[csr[rs + i] * 64 + lane];
    float v = dinv[node] * acc + b1[lane];
    float hv = silu_f(v) + r1h[node * 64 + lane] * alpha1[0];
    r1h[node * 64 + lane] = hv;
}

// h2s = (h @ W2) * dinv ; r2 = silu(h @ Wr2 + br2)
extern "C" __global__ __launch_bounds__(256) void k_gemm2(
    const float* __restrict__ h, const float* __restrict__ W2, const float* __restrict__ Wr2,
    const float* __restrict__ br2, const float* __restrict__ dinv,
    float* __restrict__ h2s, float* __restrict__ r2, int n)
{
    __shared__ float wsm[64][33];
    int t = threadIdx.x;
    #pragma unroll
    for (int i = 0; i < 8; i++) {
        int idx = t + i * 256;
        int k = idx >> 5, c = idx & 31;
        wsm[k][c] = (c < 16) ? W2[k * 16 + c] : Wr2[k * 16 + (c - 16)];
    }
    __syncthreads();
    int row = blockIdx.x * 8 + (t >> 5);
    int col = t & 31;
    if (row >= n) return;
    float acc = 0.0f;
    const float* hr = &h[(size_t)row * 64];
    #pragma unroll
    for (int k = 0; k < 64; k++) acc += hr[k] * wsm[k][col];
    float dv = dinv[row];
    if (col < 16) {
        h2s[row * 16 + col] = acc * dv;
    } else {
        float v = acc + br2[col - 16];
        r2[row * 16 + (col - 16)] = silu_f(v);
    }
}

// z = dinv[dst]*(sum h2s + h2s[dst]) + b2 + r2*alpha2 ; in place over r2
extern "C" __global__ __launch_bounds__(256) void k_agg2(
    const float* __restrict__ h2s, const int* __restrict__ rowstart, const int* __restrict__ deg,
    const int* __restrict__ csr, const float* __restrict__ dinv, const float* __restrict__ b2,
    const float* __restrict__ alpha2, float* __restrict__ r2z, int n)
{
    int wave = threadIdx.x >> 6, lane = threadIdx.x & 63;
    int node = blockIdx.x * 4 + wave;
    if (node >= n) return;
    int rs = rowstart[node], cnt = deg[node];
    int sub = lane >> 4, j = lane & 15;      // 4 edges per iteration, 16 feats each
    float acc = 0.0f;
    for (int i = sub; i < cnt; i += 4)
        acc += h2s[csr[rs + i] * 16 + j];
    acc += __shfl_xor(acc, 16, 64);
    acc += __shfl_xor(acc, 32, 64);
    if (sub == 0) {
        acc += h2s[node * 16 + j];           // self loop
        float v = dinv[node] * acc + b2[j] + r2z[node * 16 + j] * alpha2[0];
        r2z[node * 16 + j] = v;
    }
}

// graph mean pool: one block per graph, binary search on sorted batch
extern "C" __global__ __launch_bounds__(256) void k_pool(
    const float* __restrict__ z, const int* __restrict__ batch, float* __restrict__ emb, int n)
{
    int g = blockIdx.x;
    int lo = 0, hi = n;
    while (lo < hi) { int m = (lo + hi) >> 1; if (batch[m] < g) lo = m + 1; else hi = m; }
    int start = lo;
    lo = start; hi = n;
    while (lo < hi) { int m = (lo + hi) >> 1; if (batch[m] < g + 1) lo = m + 1; else hi = m; }
    int end = lo;
    int j = threadIdx.x & 15, grp = threadIdx.x >> 4;
    float acc = 0.0f;
    for (int r = start + grp; r < end; r += 16) acc += z[(size_t)r * 16 + j];
    __shared__ float part[16][17];
    part[grp][j] = acc;
    __syncthreads();
    if (threadIdx.x < 16) {
        float s = 0.0f;
        #pragma unroll
        for (int q = 0; q < 16; q++) s += part[q][threadIdx.x];
        float cnt = (float)(end - start);
        emb[g * 16 + threadIdx.x] = s / fmaxf(cnt, 1.0f);
    }
}

// 4 tiny MLPs: Linear(1,8)->SiLU->Linear(8,16); metrics[64] = concat over 4 metrics
extern "C" __global__ void k_metrics(
    const float* __restrict__ tol, const float* __restrict__ cost,
    const float* __restrict__ time_, const float* __restrict__ qty,
    const float* __restrict__ mW1, const float* __restrict__ mb1,
    const float* __restrict__ mW2, const float* __restrict__ mb2,
    float* __restrict__ metrics)
{
    int t = threadIdx.x;
    if (t >= 64) return;
    int i = t >> 4, j = t & 15;
    float mv = (i == 0) ? tol[0] : (i == 1) ? cost[0] : (i == 2) ? time_[0] : qty[0];
    float acc = mb2[i * 16 + j];
    #pragma unroll
    for (int k = 0; k < 8; k++) {
        float hpre = mv * mW1[i * 8 + k] + mb1[i * 8 + k];
        acc += silu_f(hpre) * mW2[i * 128 + k * 16 + j];
    }
    metrics[t] = acc;
}

// head: combined[80] = [emb(16) | metrics(64)] -> silu(@Wf1+bf1) -> @Wf2+bf2
extern "C" __global__ __launch_bounds__(128) void k_head(
    const float* __restrict__ emb, const float* __restrict__ metrics,
    const float* __restrict__ Wf1, const float* __restrict__ bf1,
    const float* __restrict__ Wf2, const float* __restrict__ bf2,
    float* __restrict__ out, int NC)
{
    int g = blockIdx.x;
    __shared__ float c[80], hidden[80];
    int t = threadIdx.x;
    if (t < 16) c[t] = emb[g * 16 + t];
    else if (t < 80) c[t] = metrics[t - 16];
    __syncthreads();
    if (t < 80) {
        float acc = bf1[t];
        #pragma unroll 8
        for (int k = 0; k < 80; k++) acc += c[k] * Wf1[k * 80 + t];
        hidden[t] = silu_f(acc);
    }
    __syncthreads();
    if (t < NC) {
        float acc = bf2[t];
        #pragma unroll 8
        for (int k = 0; k < 80; k++) acc += hidden[k] * Wf2[k * NC + t];
        out[g * NC + t] = acc;
    }
}

extern "C" void kernel_launch(void* const* d_in, const int* in_sizes, int n_in,
                              void* d_out, int out_size, void* d_ws, size_t ws_size,
                              hipStream_t stream)
{
    const float* x     = (const float*)d_in[0];
    const int*   ei    = (const int*)d_in[1];
    const int*   batch = (const int*)d_in[2];
    const float* tol   = (const float*)d_in[3];
    const float* cost  = (const float*)d_in[4];
    const float* time_ = (const float*)d_in[5];
    const float* qty   = (const float*)d_in[6];
    const float* W1    = (const float*)d_in[7];
    const float* Wr1   = (const float*)d_in[11];
    const float* b1    = (const float*)d_in[8];
    const float* br1   = (const float*)d_in[12];
    const float* W2    = (const float*)d_in[9];
    const float* b2    = (const float*)d_in[10];
    const float* Wr2   = (const float*)d_in[13];
    const float* br2   = (const float*)d_in[14];
    const float* alpha1= (const float*)d_in[15];
    const float* alpha2= (const float*)d_in[16];
    const float* mW1   = (const float*)d_in[17];
    const float* mb1   = (const float*)d_in[18];
    const float* mW2   = (const float*)d_in[19];
    const float* mb2   = (const float*)d_in[20];
    const float* Wf1   = (const float*)d_in[21];
    const float* bf1   = (const float*)d_in[22];
    const float* Wf2   = (const float*)d_in[23];
    const float* bf2   = (const float*)d_in[24];

    const int N  = in_sizes[2];
    const int E  = in_sizes[1] / 2;
    const int NC = in_sizes[24];
    const int G  = out_size / NC;

    const int* srcIdx = ei;
    const int* dstIdx = ei + E;

    char* w = (char*)d_ws;
    auto alloc = [&](size_t bytes) { char* p = w; w += (bytes + 255) & ~(size_t)255; return p; };
    int*   deg      = (int*)alloc((size_t)N * 4);
    int*   rowstart = (int*)alloc((size_t)N * 4);
    int*   cursor   = (int*)alloc((size_t)N * 4);
    int*   bsum     = (int*)alloc(4096);
    int*   csr      = (int*)alloc((size_t)E * 4);
    float* dinv     = (float*)alloc((size_t)N * 4);
    float* bufA     = (float*)alloc((size_t)N * 64 * 4);  // h0s, later h2s
    float* bufB     = (float*)alloc((size_t)N * 64 * 4);  // r1, later h (in place)
    float* bufC     = (float*)alloc((size_t)N * 16 * 4);  // r2, later z (in place)
    float* emb      = (float*)alloc((size_t)G * 16 * 4);
    float* metricsv = (float*)alloc(256);

    hipMemsetAsync(deg, 0, (size_t)N * 4, stream);
    hipMemsetAsync(cursor, 0, (size_t)N * 4, stream);

    int eb = (E + 255) / 256;
    int nb = (N + 255) / 256;
    int NB = (N + 1023) / 1024;

    k_deg<<<eb, 256, 0, stream>>>(dstIdx, deg, E);
    k_dinv<<<nb, 256, 0, stream>>>(deg, dinv, N);
    k_scan_partial<<<NB, 256, 0, stream>>>(deg, bsum, N);
    k_scan_bsum<<<1, 64, 0, stream>>>(bsum, NB);
    k_scan_write<<<NB, 256, 0, stream>>>(deg, bsum, rowstart, N);
    k_fill<<<eb, 256, 0, stream>>>(srcIdx, dstIdx, rowstart, cursor, csr, E);

    k_gemm1<<<(N + 63) / 64, 256, 0, stream>>>(x, W1, Wr1, br1, dinv, bufA, bufB, N);
    k_agg1<<<(N + 3) / 4, 256, 0, stream>>>(bufA, rowstart, deg, csr, dinv, b1, alpha1, bufB, N);
    k_gemm2<<<(N + 7) / 8, 256, 0, stream>>>(bufB, W2, Wr2, br2, dinv, bufA, bufC, N);
    k_agg2<<<(N + 3) / 4, 256, 0, stream>>>(bufA, rowstart, deg, csr, dinv, b2, alpha2, bufC, N);
    k_pool<<<G, 256, 0, stream>>>(bufC, batch, emb, N);
    k_metrics<<<1, 64, 0, stream>>>(tol, cost, time_, qty, mW1, mb1, mW2, mb2, metricsv);
    k_head<<<G, 128, 0, stream>>>(emb, metricsv, Wf1, bf1, Wf2, bf2, (float*)d_out, NC);
}

// Round 2
// 410.639 us; speedup vs baseline: 1.1989x; 1.1989x over previous
//
#include <hip/hip_runtime.h>

static __device__ __forceinline__ float silu_f(float v) {
    return v / (1.0f + __expf(-v));
}

extern "C" __global__ void k_deg(const int* __restrict__ dst, int* __restrict__ deg, int E) {
    int e = blockIdx.x * 256 + threadIdx.x;
    if (e < E) atomicAdd(&deg[dst[e]], 1);
}

extern "C" __global__ void k_dinv(const int* __restrict__ deg, float* __restrict__ dinv, int n) {
    int i = blockIdx.x * 256 + threadIdx.x;
    if (i < n) dinv[i] = rsqrtf((float)(deg[i] + 1));   // +1 = self loop
}

extern "C" __global__ void k_scan_partial(const int* __restrict__ deg, int* __restrict__ bsum, int n) {
    int base = blockIdx.x * 1024;
    int s = 0;
    for (int i = threadIdx.x; i < 1024; i += 256) {
        int idx = base + i;
        s += (idx < n) ? deg[idx] : 0;
    }
    for (int off = 1; off < 64; off <<= 1) s += __shfl_xor(s, off, 64);
    __shared__ int wsum[4];
    if ((threadIdx.x & 63) == 0) wsum[threadIdx.x >> 6] = s;
    __syncthreads();
    if (threadIdx.x == 0) bsum[blockIdx.x] = wsum[0] + wsum[1] + wsum[2] + wsum[3];
}

extern "C" __global__ void k_scan_bsum(int* __restrict__ bsum, int nb) {
    if (threadIdx.x == 0 && blockIdx.x == 0) {
        int run = 0;
        for (int i = 0; i < nb; i++) { int v = bsum[i]; bsum[i] = run; run += v; }
    }
}

extern "C" __global__ void k_scan_write(const int* __restrict__ deg, const int* __restrict__ bsum,
                                        int* __restrict__ rowstart, int n) {
    int t = threadIdx.x;
    int base = blockIdx.x * 1024;
    int v[4], loc[4];
    int s = 0;
    #pragma unroll
    for (int i = 0; i < 4; i++) {
        int idx = base + t * 4 + i;
        v[i] = (idx < n) ? deg[idx] : 0;
        loc[i] = s; s += v[i];
    }
    __shared__ int sc[256];
    sc[t] = s;
    __syncthreads();
    int mine = s;
    for (int off = 1; off < 256; off <<= 1) {
        int add = (t >= off) ? sc[t - off] : 0;
        __syncthreads();
        sc[t] += add;
        __syncthreads();
    }
    int excl = sc[t] - mine + bsum[blockIdx.x];
    #pragma unroll
    for (int i = 0; i < 4; i++) {
        int idx = base + t * 4 + i;
        if (idx < n) rowstart[idx] = excl + loc[i];
    }
}

extern "C" __global__ void k_fill(const int* __restrict__ src, const int* __restrict__ dst,
                                  const int* __restrict__ rowstart, int* __restrict__ cursor,
                                  int* __restrict__ csr, int E) {
    int e = blockIdx.x * 256 + threadIdx.x;
    if (e >= E) return;
    int d = dst[e];
    int pos = atomicAdd(&cursor[d], 1);
    csr[rowstart[d] + pos] = src[e];
}

// h0s = (x @ W1) * dinv[row] ; r1 = silu(x @ Wr1 + br1)
// 128x128 block tile, 8x8 per-thread register tile, 4x ds_read_b128 per k-step.
extern "C" __global__ __launch_bounds__(256, 4) void k_gemm1(
    const float* __restrict__ x, const float* __restrict__ W1, const float* __restrict__ Wr1,
    const float* __restrict__ br1, const float* __restrict__ dinv,
    float* __restrict__ h0s, float* __restrict__ r1, int n)
{
    __shared__ float xsT[32 * 132];   // [k][row], pitch 132 floats
    __shared__ float wsm[32 * 128];   // [k][32 float4 units, XOR-swizzled]
    int t = threadIdx.x;
    int r0 = blockIdx.x * 128;
    int rg = t >> 4;                  // rows rg*8..+7
    int cg = t & 15;                  // cols cg*8..+7
    float acc[8][8] = {};

    int acg = cg >> 2;
    int p0 = (2 * cg) ^ acg;          // swizzled float4 unit for cols 8cg..8cg+3
    const float* xbase  = &xsT[rg * 8];
    const float* wbase0 = &wsm[p0 * 4];
    const float* wbase1 = &wsm[(p0 ^ 1) * 4];

    for (int kk = 0; kk < 128; kk += 32) {
        #pragma unroll
        for (int i = 0; i < 4; i++) {            // stage x transposed
            int u = t + i * 256;                 // 1024 float4 units
            int row = u >> 3, kq = u & 7;
            float4 v = make_float4(0.f, 0.f, 0.f, 0.f);
            int grow = r0 + row;
            if (grow < n) v = *(const float4*)&x[(size_t)grow * 128 + kk + kq * 4];
            xsT[(kq * 4 + 0) * 132 + row] = v.x;
            xsT[(kq * 4 + 1) * 132 + row] = v.y;
            xsT[(kq * 4 + 2) * 132 + row] = v.z;
            xsT[(kq * 4 + 3) * 132 + row] = v.w;
        }
        #pragma unroll
        for (int i = 0; i < 4; i++) {            // stage [W1|Wr1], swizzled units
            int ul = t + i * 256;                // 1024 float4 units
            int k = ul >> 5, u = ul & 31;
            int c = u * 4;
            float4 v;
            if (c < 64) v = *(const float4*)&W1[(size_t)(kk + k) * 64 + c];
            else        v = *(const float4*)&Wr1[(size_t)(kk + k) * 64 + (c - 64)];
            int p = u ^ ((u >> 3) & 3);
            *(float4*)&wsm[k * 128 + p * 4] = v;
        }
        __syncthreads();
        #pragma unroll
        for (int k = 0; k < 32; k++) {
            float4 xa = *(const float4*)&xbase[k * 132];
            float4 xb = *(const float4*)&xbase[k * 132 + 4];
            float4 wa = *(const float4*)&wbase0[k * 128];
            float4 wb = *(const float4*)&wbase1[k * 128];
            float xv[8] = {xa.x, xa.y, xa.z, xa.w, xb.x, xb.y, xb.z, xb.w};
            float wv[8] = {wa.x, wa.y, wa.z, wa.w, wb.x, wb.y, wb.z, wb.w};
            #pragma unroll
            for (int i = 0; i < 8; i++)
                #pragma unroll
                for (int j = 0; j < 8; j++) acc[i][j] += xv[i] * wv[j];
        }
        __syncthreads();
    }

    if (cg < 8) {                                 // h0s cols 0..63
        int c0 = cg * 8;
        #pragma unroll
        for (int i = 0; i < 8; i++) {
            int row = r0 + rg * 8 + i;
            if (row >= n) break;
            float dv = dinv[row];
            float4 o0 = make_float4(acc[i][0]*dv, acc[i][1]*dv, acc[i][2]*dv, acc[i][3]*dv);
            float4 o1 = make_float4(acc[i][4]*dv, acc[i][5]*dv, acc[i][6]*dv, acc[i][7]*dv);
            *(float4*)&h0s[(size_t)row * 64 + c0]     = o0;
            *(float4*)&h0s[(size_t)row * 64 + c0 + 4] = o1;
        }
    } else {                                      // r1 cols 0..63
        int c0 = (cg - 8) * 8;
        float4 ba = *(const float4*)&br1[c0];
        float4 bb = *(const float4*)&br1[c0 + 4];
        #pragma unroll
        for (int i = 0; i < 8; i++) {
            int row = r0 + rg * 8 + i;
            if (row >= n) break;
            float4 o0 = make_float4(silu_f(acc[i][0]+ba.x), silu_f(acc[i][1]+ba.y),
                                    silu_f(acc[i][2]+ba.z), silu_f(acc[i][3]+ba.w));
            float4 o1 = make_float4(silu_f(acc[i][4]+bb.x), silu_f(acc[i][5]+bb.y),
                                    silu_f(acc[i][6]+bb.z), silu_f(acc[i][7]+bb.w));
            *(float4*)&r1[(size_t)row * 64 + c0]     = o0;
            *(float4*)&r1[(size_t)row * 64 + c0 + 4] = o1;
        }
    }
}

// h = silu(dinv[dst]*(sum_src h0s + h0s[dst]) + b1) + r1*alpha1 ; in place over r1
extern "C" __global__ __launch_bounds__(256) void k_agg1(
    const float* __restrict__ h0s, const int* __restrict__ rowstart, const int* __restrict__ deg,
    const int* __restrict__ csr, const float* __restrict__ dinv, const float* __restrict__ b1,
    const float* __restrict__ alpha1, float* __restrict__ r1h, int n)
{
    int wave = threadIdx.x >> 6, lane = threadIdx.x & 63;
    int node = blockIdx.x * 4 + wave;
    if (node >= n) return;
    int rs = rowstart[node];
    int cnt = deg[node];
    float acc = h0s[(size_t)node * 64 + lane];   // self loop
    int i = 0;
    for (; i + 8 <= cnt; i += 8) {               // 8 gathers in flight
        int s0 = csr[rs+i+0], s1 = csr[rs+i+1], s2 = csr[rs+i+2], s3 = csr[rs+i+3];
        int s4 = csr[rs+i+4], s5 = csr[rs+i+5], s6 = csr[rs+i+6], s7 = csr[rs+i+7];
        float a0 = h0s[(size_t)s0*64+lane], a1 = h0s[(size_t)s1*64+lane];
        float a2 = h0s[(size_t)s2*64+lane], a3 = h0s[(size_t)s3*64+lane];
        float a4 = h0s[(size_t)s4*64+lane], a5 = h0s[(size_t)s5*64+lane];
        float a6 = h0s[(size_t)s6*64+lane], a7 = h0s[(size_t)s7*64+lane];
        acc += ((a0+a1)+(a2+a3)) + ((a4+a5)+(a6+a7));
    }
    for (; i < cnt; i++) acc += h0s[(size_t)csr[rs+i]*64+lane];
    float v = dinv[node] * acc + b1[lane];
    float hv = silu_f(v) + r1h[(size_t)node * 64 + lane] * alpha1[0];
    r1h[(size_t)node * 64 + lane] = hv;
}

// h2s = (h @ W2) * dinv ; r2 = silu(h @ Wr2 + br2)
// 128-row block, 32 output cols, 4x4 per-thread tile, 2x ds_read_b128 per k-step.
extern "C" __global__ __launch_bounds__(256, 4) void k_gemm2(
    const float* __restrict__ h, const float* __restrict__ W2, const float* __restrict__ Wr2,
    const float* __restrict__ br2, const float* __restrict__ dinv,
    float* __restrict__ h2s, float* __restrict__ r2, int n)
{
    __shared__ float xsT[64 * 132];   // [k][row]
    __shared__ float wsm[64 * 32];    // [k][c]
    int t = threadIdx.x;
    int r0 = blockIdx.x * 128;
    int rg = t >> 3;                  // 0..31, rows rg*4..+3
    int cg = t & 7;                   // cols cg*4..+3
    float acc[4][4] = {};

    #pragma unroll
    for (int i = 0; i < 8; i++) {     // stage h transposed: 2048 float4
        int u = t + i * 256;
        int row = u >> 4, kq = u & 15;
        float4 v = make_float4(0.f, 0.f, 0.f, 0.f);
        int grow = r0 + row;
        if (grow < n) v = *(const float4*)&h[(size_t)grow * 64 + kq * 4];
        xsT[(kq * 4 + 0) * 132 + row] = v.x;
        xsT[(kq * 4 + 1) * 132 + row] = v.y;
        xsT[(kq * 4 + 2) * 132 + row] = v.z;
        xsT[(kq * 4 + 3) * 132 + row] = v.w;
    }
    #pragma unroll
    for (int i = 0; i < 2; i++) {     // stage [W2|Wr2]: 512 float4
        int ul = t + i * 256;
        int k = ul >> 3, u = ul & 7;
        int c = u * 4;
        float4 v;
        if (c < 16) v = *(const float4*)&W2[(size_t)k * 16 + c];
        else        v = *(const float4*)&Wr2[(size_t)k * 16 + (c - 16)];
        *(float4*)&wsm[k * 32 + c] = v;
    }
    __syncthreads();

    const float* xbase = &xsT[rg * 4];
    const float* wbase = &wsm[cg * 4];
    #pragma unroll
    for (int k = 0; k < 64; k++) {
        float4 xa = *(const float4*)&xbase[k * 132];
        float4 wa = *(const float4*)&wbase[k * 32];
        float xv[4] = {xa.x, xa.y, xa.z, xa.w};
        float wv[4] = {wa.x, wa.y, wa.z, wa.w};
        #pragma unroll
        for (int i = 0; i < 4; i++)
            #pragma unroll
            for (int j = 0; j < 4; j++) acc[i][j] += xv[i] * wv[j];
    }

    if (cg < 4) {                     // h2s cols 0..15
        int c0 = cg * 4;
        #pragma unroll
        for (int i = 0; i < 4; i++) {
            int row = r0 + rg * 4 + i;
            if (row >= n) break;
            float dv = dinv[row];
            float4 o = make_float4(acc[i][0]*dv, acc[i][1]*dv, acc[i][2]*dv, acc[i][3]*dv);
            *(float4*)&h2s[(size_t)row * 16 + c0] = o;
        }
    } else {                          // r2 cols 0..15
        int c0 = (cg - 4) * 4;
        float4 b = *(const float4*)&br2[c0];
        #pragma unroll
        for (int i = 0; i < 4; i++) {
            int row = r0 + rg * 4 + i;
            if (row >= n) break;
            float4 o = make_float4(silu_f(acc[i][0]+b.x), silu_f(acc[i][1]+b.y),
                                   silu_f(acc[i][2]+b.z), silu_f(acc[i][3]+b.w));
            *(float4*)&r2[(size_t)row * 16 + c0] = o;
        }
    }
}

// z = dinv[dst]*(sum h2s + h2s[dst]) + b2 + r2*alpha2 ; in place over r2
extern "C" __global__ __launch_bounds__(256) void k_agg2(
    const float* __restrict__ h2s, const int* __restrict__ rowstart, const int* __restrict__ deg,
    const int* __restrict__ csr, const float* __restrict__ dinv, const float* __restrict__ b2,
    const float* __restrict__ alpha2, float* __restrict__ r2z, int n)
{
    int wave = threadIdx.x >> 6, lane = threadIdx.x & 63;
    int node = blockIdx.x * 4 + wave;
    if (node >= n) return;
    int rs = rowstart[node], cnt = deg[node];
    int sub = lane >> 4, j = lane & 15;      // 4 edges per iteration, 16 feats each
    float acc = 0.0f;
    int i = sub;
    for (; i + 8 <= cnt; i += 8) {
        int sa = csr[rs + i], sb = csr[rs + i + 4];
        acc += h2s[(size_t)sa * 16 + j] + h2s[(size_t)sb * 16 + j];
    }
    for (; i < cnt; i += 4) acc += h2s[(size_t)csr[rs + i] * 16 + j];
    acc += __shfl_xor(acc, 16, 64);
    acc += __shfl_xor(acc, 32, 64);
    if (sub == 0) {
        acc += h2s[(size_t)node * 16 + j];   // self loop
        float v = dinv[node] * acc + b2[j] + r2z[(size_t)node * 16 + j] * alpha2[0];
        r2z[(size_t)node * 16 + j] = v;
    }
}

// graph mean pool: one block per graph, binary search on sorted batch
extern "C" __global__ __launch_bounds__(256) void k_pool(
    const float* __restrict__ z, const int* __restrict__ batch, float* __restrict__ emb, int n)
{
    int g = blockIdx.x;
    int lo = 0, hi = n;
    while (lo < hi) { int m = (lo + hi) >> 1; if (batch[m] < g) lo = m + 1; else hi = m; }
    int start = lo;
    lo = start; hi = n;
    while (lo < hi) { int m = (lo + hi) >> 1; if (batch[m] < g + 1) lo = m + 1; else hi = m; }
    int end = lo;
    int j = threadIdx.x & 15, grp = threadIdx.x >> 4;
    float acc = 0.0f;
    for (int r = start + grp; r < end; r += 16) acc += z[(size_t)r * 16 + j];
    __shared__ float part[16][17];
    part[grp][j] = acc;
    __syncthreads();
    if (threadIdx.x < 16) {
        float s = 0.0f;
        #pragma unroll
        for (int q = 0; q < 16; q++) s += part[q][threadIdx.x];
        float cnt = (float)(end - start);
        emb[g * 16 + threadIdx.x] = s / fmaxf(cnt, 1.0f);
    }
}

extern "C" __global__ void k_metrics(
    const float* __restrict__ tol, const float* __restrict__ cost,
    const float* __restrict__ time_, const float* __restrict__ qty,
    const float* __restrict__ mW1, const float* __restrict__ mb1,
    const float* __restrict__ mW2, const float* __restrict__ mb2,
    float* __restrict__ metrics)
{
    int t = threadIdx.x;
    if (t >= 64) return;
    int i = t >> 4, j = t & 15;
    float mv = (i == 0) ? tol[0] : (i == 1) ? cost[0] : (i == 2) ? time_[0] : qty[0];
    float acc = mb2[i * 16 + j];
    #pragma unroll
    for (int k = 0; k < 8; k++) {
        float hpre = mv * mW1[i * 8 + k] + mb1[i * 8 + k];
        acc += silu_f(hpre) * mW2[i * 128 + k * 16 + j];
    }
    metrics[t] = acc;
}

extern "C" __global__ __launch_bounds__(128) void k_head(
    const float* __restrict__ emb, const float* __restrict__ metrics,
    const float* __restrict__ Wf1, const float* __restrict__ bf1,
    const float* __restrict__ Wf2, const float* __restrict__ bf2,
    float* __restrict__ out, int NC)
{
    int g = blockIdx.x;
    __shared__ float c[80], hidden[80];
    int t = threadIdx.x;
    if (t < 16) c[t] = emb[g * 16 + t];
    else if (t < 80) c[t] = metrics[t - 16];
    __syncthreads();
    if (t < 80) {
        float acc = bf1[t];
        #pragma unroll 8
        for (int k = 0; k < 80; k++) acc += c[k] * Wf1[k * 80 + t];
        hidden[t] = silu_f(acc);
    }
    __syncthreads();
    if (t < NC) {
        float acc = bf2[t];
        #pragma unroll 8
        for (int k = 0; k < 80; k++) acc += hidden[k] * Wf2[k * NC + t];
        out[g * NC + t] = acc;
    }
}

extern "C" void kernel_launch(void* const* d_in, const int* in_sizes, int n_in,
                              void* d_out, int out_size, void* d_ws, size_t ws_size,
                              hipStream_t stream)
{
    const float* x     = (const float*)d_in[0];
    const int*   ei    = (const int*)d_in[1];
    const int*   batch = (const int*)d_in[2];
    const float* tol   = (const float*)d_in[3];
    const float* cost  = (const float*)d_in[4];
    const float* time_ = (const float*)d_in[5];
    const float* qty   = (const float*)d_in[6];
    const float* W1    = (const float*)d_in[7];
    const float* b1    = (const float*)d_in[8];
    const float* W2    = (const float*)d_in[9];
    const float* b2    = (const float*)d_in[10];
    const float* Wr1   = (const float*)d_in[11];
    const float* br1   = (const float*)d_in[12];
    const float* Wr2   = (const float*)d_in[13];
    const float* br2   = (const float*)d_in[14];
    const float* alpha1= (const float*)d_in[15];
    const float* alpha2= (const float*)d_in[16];
    const float* mW1   = (const float*)d_in[17];
    const float* mb1   = (const float*)d_in[18];
    const float* mW2   = (const float*)d_in[19];
    const float* mb2   = (const float*)d_in[20];
    const float* Wf1   = (const float*)d_in[21];
    const float* bf1   = (const float*)d_in[22];
    const float* Wf2   = (const float*)d_in[23];
    const float* bf2   = (const float*)d_in[24];

    const int N  = in_sizes[2];
    const int E  = in_sizes[1] / 2;
    const int NC = in_sizes[24];

    const int* srcIdx = ei;
    const int* dstIdx = ei + E;

    char* w = (char*)d_ws;
    auto alloc = [&](size_t bytes) { char* p = w; w += (bytes + 255) & ~(size_t)255; return p; };
    int*   deg      = (int*)alloc((size_t)N * 4);
    int*   rowstart = (int*)alloc((size_t)N * 4);
    int*   cursor   = (int*)alloc((size_t)N * 4);
    int*   bsum     = (int*)alloc(4096);
    int*   csr      = (int*)alloc((size_t)E * 4);
    float* dinv     = (float*)alloc((size_t)N * 4);
    float* bufA     = (float*)alloc((size_t)N * 64 * 4);  // h0s, later h2s
    float* bufB     = (float*)alloc((size_t)N * 64 * 4);  // r1, later h (in place)
    float* bufC     = (float*)alloc((size_t)N * 16 * 4);  // r2, later z (in place)
    const int G = out_size / NC;
    float* emb      = (float*)alloc((size_t)G * 16 * 4);
    float* metricsv = (float*)alloc(256);

    hipMemsetAsync(deg, 0, (size_t)N * 4, stream);
    hipMemsetAsync(cursor, 0, (size_t)N * 4, stream);

    int eb = (E + 255) / 256;
    int nb = (N + 255) / 256;
    int NB = (N + 1023) / 1024;

    k_deg<<<eb, 256, 0, stream>>>(dstIdx, deg, E);
    k_dinv<<<nb, 256, 0, stream>>>(deg, dinv, N);
    k_scan_partial<<<NB, 256, 0, stream>>>(deg, bsum, N);
    k_scan_bsum<<<1, 64, 0, stream>>>(bsum, NB);
    k_scan_write<<<NB, 256, 0, stream>>>(deg, bsum, rowstart, N);
    k_fill<<<eb, 256, 0, stream>>>(srcIdx, dstIdx, rowstart, cursor, csr, E);

    k_gemm1<<<(N + 127) / 128, 256, 0, stream>>>(x, W1, Wr1, br1, dinv, bufA, bufB, N);
    k_agg1<<<(N + 3) / 4, 256, 0, stream>>>(bufA, rowstart, deg, csr, dinv, b1, alpha1, bufB, N);
    k_gemm2<<<(N + 127) / 128, 256, 0, stream>>>(bufB, W2, Wr2, br2, dinv, bufA, bufC, N);
    k_agg2<<<(N + 3) / 4, 256, 0, stream>>>(bufA, rowstart, deg, csr, dinv, b2, alpha2, bufC, N);
    k_pool<<<G, 256, 0, stream>>>(bufC, batch, emb, N);
    k_metrics<<<1, 64, 0, stream>>>(tol, cost, time_, qty, mW1, mb1, mW2, mb2, metricsv);
    k_head<<<G, 128, 0, stream>>>(emb, metricsv, Wf1, bf1, Wf2, bf2, (float*)d_out, NC);
}

// Round 3
// 310.820 us; speedup vs baseline: 1.5839x; 1.3211x over previous
//
#include <hip/hip_runtime.h>

static __device__ __forceinline__ float silu_f(float v) {
    return v / (1.0f + __expf(-v));
}

// ---------------- bucketed CSR build ----------------
// Buckets = dst >> shift, sized so nbkt <= 512. Edges are partitioned into a
// dst-bucketed edge buffer (block-local contiguous writes), then each bucket's
// CSR window (~16KB) is filled by one block with LDS cursors (L2-resident).

extern "C" __global__ __launch_bounds__(256) void k_bhist(
    const int* __restrict__ dst, int* __restrict__ bcount, int E, int nbkt, int shift)
{
    __shared__ int lh[512];
    int t = threadIdx.x;
    for (int i = t; i < 512; i += 256) lh[i] = 0;
    __syncthreads();
    int e0 = blockIdx.x * 8192;
    #pragma unroll 4
    for (int i = 0; i < 32; i++) {
        int e = e0 + t + i * 256;
        if (e < E) atomicAdd(&lh[dst[e] >> shift], 1);
    }
    __syncthreads();
    for (int b = t; b < nbkt; b += 256)
        if (lh[b]) atomicAdd(&bcount[b], lh[b]);
}

extern "C" __global__ __launch_bounds__(512) void k_bscan(
    const int* __restrict__ bcount, int* __restrict__ boff, int* __restrict__ bcursor, int nbkt)
{
    __shared__ int sc[512];
    int t = threadIdx.x;
    int v = (t < nbkt) ? bcount[t] : 0;
    sc[t] = v;
    __syncthreads();
    for (int off = 1; off < 512; off <<= 1) {
        int add = (t >= off) ? sc[t - off] : 0;
        __syncthreads();
        sc[t] += add;
        __syncthreads();
    }
    int excl = sc[t] - v;
    if (t < nbkt) { boff[t] = excl; bcursor[t] = excl; }
    if (t == nbkt - 1) boff[nbkt] = excl + v;
}

extern "C" __global__ __launch_bounds__(256) void k_bscatter(
    const int* __restrict__ src, const int* __restrict__ dst, int* __restrict__ bcursor,
    int2* __restrict__ ebuf, int E, int nbkt, int shift)
{
    __shared__ int lh[512];
    __shared__ int lbase[512];
    int t = threadIdx.x;
    for (int i = t; i < 512; i += 256) lh[i] = 0;
    __syncthreads();
    int e0 = blockIdx.x * 8192;
    #pragma unroll 4
    for (int i = 0; i < 32; i++) {
        int e = e0 + t + i * 256;
        if (e < E) atomicAdd(&lh[dst[e] >> shift], 1);
    }
    __syncthreads();
    for (int b = t; b < nbkt; b += 256)
        lbase[b] = lh[b] ? atomicAdd(&bcursor[b], lh[b]) : 0;
    __syncthreads();
    #pragma unroll 4
    for (int i = 0; i < 32; i++) {
        int e = e0 + t + i * 256;
        if (e < E) {
            int d = dst[e];
            int p = atomicAdd(&lbase[d >> shift], 1);
            ebuf[p] = make_int2(src[e], d);
        }
    }
}

extern "C" __global__ __launch_bounds__(256) void k_bdeg(
    const int2* __restrict__ ebuf, const int* __restrict__ boff,
    int* __restrict__ deg, int shift, int N)
{
    int b = blockIdx.x;
    int W = 1 << shift;
    __shared__ int lcur[4096];
    int t = threadIdx.x;
    for (int i = t; i < W; i += 256) lcur[i] = 0;
    __syncthreads();
    int s = boff[b], e_ = boff[b + 1];
    for (int e = s + t; e < e_; e += 256)
        atomicAdd(&lcur[ebuf[e].y - (b << shift)], 1);
    __syncthreads();
    int base = b << shift;
    for (int i = t; i < W; i += 256) {
        int node = base + i;
        if (node < N) deg[node] = lcur[i];
    }
}

extern "C" __global__ __launch_bounds__(256) void k_bfill(
    const int2* __restrict__ ebuf, const int* __restrict__ boff,
    const int* __restrict__ rowstart, int* __restrict__ csr, int shift)
{
    int b = blockIdx.x;
    int W = 1 << shift;
    __shared__ int lcur[4096];
    int t = threadIdx.x;
    for (int i = t; i < W; i += 256) lcur[i] = 0;
    __syncthreads();
    int s = boff[b], e_ = boff[b + 1];
    for (int e = s + t; e < e_; e += 256) {
        int2 p = ebuf[e];
        int pos = atomicAdd(&lcur[p.y - (b << shift)], 1);
        csr[rowstart[p.y] + pos] = p.x;
    }
}

// ---------------- degree-scan (rowstart) ----------------

extern "C" __global__ void k_dinv(const int* __restrict__ deg, float* __restrict__ dinv, int n) {
    int i = blockIdx.x * 256 + threadIdx.x;
    if (i < n) dinv[i] = rsqrtf((float)(deg[i] + 1));   // +1 = self loop
}

extern "C" __global__ void k_scan_partial(const int* __restrict__ deg, int* __restrict__ bsum, int n) {
    int base = blockIdx.x * 1024;
    int s = 0;
    for (int i = threadIdx.x; i < 1024; i += 256) {
        int idx = base + i;
        s += (idx < n) ? deg[idx] : 0;
    }
    for (int off = 1; off < 64; off <<= 1) s += __shfl_xor(s, off, 64);
    __shared__ int wsum[4];
    if ((threadIdx.x & 63) == 0) wsum[threadIdx.x >> 6] = s;
    __syncthreads();
    if (threadIdx.x == 0) bsum[blockIdx.x] = wsum[0] + wsum[1] + wsum[2] + wsum[3];
}

extern "C" __global__ void k_scan_bsum(int* __restrict__ bsum, int nb) {
    if (threadIdx.x == 0 && blockIdx.x == 0) {
        int run = 0;
        for (int i = 0; i < nb; i++) { int v = bsum[i]; bsum[i] = run; run += v; }
    }
}

extern "C" __global__ void k_scan_write(const int* __restrict__ deg, const int* __restrict__ bsum,
                                        int* __restrict__ rowstart, int n) {
    int t = threadIdx.x;
    int base = blockIdx.x * 1024;
    int v[4], loc[4];
    int s = 0;
    #pragma unroll
    for (int i = 0; i < 4; i++) {
        int idx = base + t * 4 + i;
        v[i] = (idx < n) ? deg[idx] : 0;
        loc[i] = s; s += v[i];
    }
    __shared__ int sc[256];
    sc[t] = s;
    __syncthreads();
    int mine = s;
    for (int off = 1; off < 256; off <<= 1) {
        int add = (t >= off) ? sc[t - off] : 0;
        __syncthreads();
        sc[t] += add;
        __syncthreads();
    }
    int excl = sc[t] - mine + bsum[blockIdx.x];
    #pragma unroll
    for (int i = 0; i < 4; i++) {
        int idx = base + t * 4 + i;
        if (idx < n) rowstart[idx] = excl + loc[i];
    }
}

// ---------------- fused GEMMs ----------------
// h0s = (x @ W1) * dinv[row] ; r1 = silu(x @ Wr1 + br1)
// 128x128 block tile, 8x8 per-thread register tile, 4x ds_read_b128 per k-step.
extern "C" __global__ __launch_bounds__(256) void k_gemm1(
    const float* __restrict__ x, const float* __restrict__ W1, const float* __restrict__ Wr1,
    const float* __restrict__ br1, const float* __restrict__ dinv,
    float* __restrict__ h0s, float* __restrict__ r1, int n)
{
    __shared__ float xsT[32 * 132];   // [k][row], pitch 132 floats (16B-aligned rows)
    __shared__ float wsm[32 * 128];   // [k][32 float4 units, XOR-swizzled]
    int t = threadIdx.x;
    int r0 = blockIdx.x * 128;
    int rg = t >> 4;                  // rows rg*8..+7
    int cg = t & 15;                  // cols cg*8..+7
    float acc[8][8] = {};

    int acg = cg >> 2;
    int p0 = (2 * cg) ^ acg;          // swizzled float4 unit for cols 8cg..8cg+3
    const float* xbase  = &xsT[rg * 8];
    const float* wbase0 = &wsm[p0 * 4];
    const float* wbase1 = &wsm[(p0 ^ 1) * 4];

    for (int kk = 0; kk < 128; kk += 32) {
        #pragma unroll
        for (int i = 0; i < 4; i++) {            // stage x transposed
            int u = t + i * 256;                 // 1024 float4 units
            int row = u >> 3, kq = u & 7;
            float4 v = make_float4(0.f, 0.f, 0.f, 0.f);
            int grow = r0 + row;
            if (grow < n) v = *(const float4*)&x[(size_t)grow * 128 + kk + kq * 4];
            xsT[(kq * 4 + 0) * 132 + row] = v.x;
            xsT[(kq * 4 + 1) * 132 + row] = v.y;
            xsT[(kq * 4 + 2) * 132 + row] = v.z;
            xsT[(kq * 4 + 3) * 132 + row] = v.w;
        }
        #pragma unroll
        for (int i = 0; i < 4; i++) {            // stage [W1|Wr1], swizzled units
            int ul = t + i * 256;                // 1024 float4 units
            int k = ul >> 5, u = ul & 31;
            int c = u * 4;
            float4 v;
            if (c < 64) v = *(const float4*)&W1[(size_t)(kk + k) * 64 + c];
            else        v = *(const float4*)&Wr1[(size_t)(kk + k) * 64 + (c - 64)];
            int p = u ^ ((u >> 3) & 3);
            *(float4*)&wsm[k * 128 + p * 4] = v;
        }
        __syncthreads();
        #pragma unroll
        for (int k = 0; k < 32; k++) {
            float4 xa = *(const float4*)&xbase[k * 132];
            float4 xb = *(const float4*)&xbase[k * 132 + 4];
            float4 wa = *(const float4*)&wbase0[k * 128];
            float4 wb = *(const float4*)&wbase1[k * 128];
            float xv[8] = {xa.x, xa.y, xa.z, xa.w, xb.x, xb.y, xb.z, xb.w};
            float wv[8] = {wa.x, wa.y, wa.z, wa.w, wb.x, wb.y, wb.z, wb.w};
            #pragma unroll
            for (int i = 0; i < 8; i++)
                #pragma unroll
                for (int j = 0; j < 8; j++) acc[i][j] += xv[i] * wv[j];
        }
        __syncthreads();
    }

    if (cg < 8) {                                 // h0s cols 0..63
        int c0 = cg * 8;
        #pragma unroll
        for (int i = 0; i < 8; i++) {
            int row = r0 + rg * 8 + i;
            if (row >= n) break;
            float dv = dinv[row];
            float4 o0 = make_float4(acc[i][0]*dv, acc[i][1]*dv, acc[i][2]*dv, acc[i][3]*dv);
            float4 o1 = make_float4(acc[i][4]*dv, acc[i][5]*dv, acc[i][6]*dv, acc[i][7]*dv);
            *(float4*)&h0s[(size_t)row * 64 + c0]     = o0;
            *(float4*)&h0s[(size_t)row * 64 + c0 + 4] = o1;
        }
    } else {                                      // r1 cols 0..63
        int c0 = (cg - 8) * 8;
        float4 ba = *(const float4*)&br1[c0];
        float4 bb = *(const float4*)&br1[c0 + 4];
        #pragma unroll
        for (int i = 0; i < 8; i++) {
            int row = r0 + rg * 8 + i;
            if (row >= n) break;
            float4 o0 = make_float4(silu_f(acc[i][0]+ba.x), silu_f(acc[i][1]+ba.y),
                                    silu_f(acc[i][2]+ba.z), silu_f(acc[i][3]+ba.w));
            float4 o1 = make_float4(silu_f(acc[i][4]+bb.x), silu_f(acc[i][5]+bb.y),
                                    silu_f(acc[i][6]+bb.z), silu_f(acc[i][7]+bb.w));
            *(float4*)&r1[(size_t)row * 64 + c0]     = o0;
            *(float4*)&r1[(size_t)row * 64 + c0 + 4] = o1;
        }
    }
}

// h = silu(dinv[dst]*(sum_src h0s + h0s[dst]) + b1) + r1*alpha1 ; in place over r1
extern "C" __global__ __launch_bounds__(256) void k_agg1(
    const float* __restrict__ h0s, const int* __restrict__ rowstart, const int* __restrict__ deg,
    const int* __restrict__ csr, const float* __restrict__ dinv, const float* __restrict__ b1,
    const float* __restrict__ alpha1, float* __restrict__ r1h, int n)
{
    int wave = threadIdx.x >> 6, lane = threadIdx.x & 63;
    int node = blockIdx.x * 4 + wave;
    if (node >= n) return;
    int rs = rowstart[node];
    int cnt = deg[node];
    float acc = h0s[(size_t)node * 64 + lane];   // self loop
    int i = 0;
    for (; i + 8 <= cnt; i += 8) {               // 8 gathers in flight
        int s0 = csr[rs+i+0], s1 = csr[rs+i+1], s2 = csr[rs+i+2], s3 = csr[rs+i+3];
        int s4 = csr[rs+i+4], s5 = csr[rs+i+5], s6 = csr[rs+i+6], s7 = csr[rs+i+7];
        float a0 = h0s[(size_t)s0*64+lane], a1 = h0s[(size_t)s1*64+lane];
        float a2 = h0s[(size_t)s2*64+lane], a3 = h0s[(size_t)s3*64+lane];
        float a4 = h0s[(size_t)s4*64+lane], a5 = h0s[(size_t)s5*64+lane];
        float a6 = h0s[(size_t)s6*64+lane], a7 = h0s[(size_t)s7*64+lane];
        acc += ((a0+a1)+(a2+a3)) + ((a4+a5)+(a6+a7));
    }
    for (; i < cnt; i++) acc += h0s[(size_t)csr[rs+i]*64+lane];
    float v = dinv[node] * acc + b1[lane];
    float hv = silu_f(v) + r1h[(size_t)node * 64 + lane] * alpha1[0];
    r1h[(size_t)node * 64 + lane] = hv;
}

// h2s = (h @ W2) * dinv ; r2 = silu(h @ Wr2 + br2)
extern "C" __global__ __launch_bounds__(256) void k_gemm2(
    const float* __restrict__ h, const float* __restrict__ W2, const float* __restrict__ Wr2,
    const float* __restrict__ br2, const float* __restrict__ dinv,
    float* __restrict__ h2s, float* __restrict__ r2, int n)
{
    __shared__ float xsT[64 * 132];   // [k][row]
    __shared__ float wsm[64 * 32];    // [k][c]
    int t = threadIdx.x;
    int r0 = blockIdx.x * 128;
    int rg = t >> 3;                  // 0..31, rows rg*4..+3
    int cg = t & 7;                   // cols cg*4..+3
    float acc[4][4] = {};

    #pragma unroll
    for (int i = 0; i < 8; i++) {     // stage h transposed: 2048 float4
        int u = t + i * 256;
        int row = u >> 4, kq = u & 15;
        float4 v = make_float4(0.f, 0.f, 0.f, 0.f);
        int grow = r0 + row;
        if (grow < n) v = *(const float4*)&h[(size_t)grow * 64 + kq * 4];
        xsT[(kq * 4 + 0) * 132 + row] = v.x;
        xsT[(kq * 4 + 1) * 132 + row] = v.y;
        xsT[(kq * 4 + 2) * 132 + row] = v.z;
        xsT[(kq * 4 + 3) * 132 + row] = v.w;
    }
    #pragma unroll
    for (int i = 0; i < 2; i++) {     // stage [W2|Wr2]: 512 float4
        int ul = t + i * 256;
        int k = ul >> 3, u = ul & 7;
        int c = u * 4;
        float4 v;
        if (c < 16) v = *(const float4*)&W2[(size_t)k * 16 + c];
        else        v = *(const float4*)&Wr2[(size_t)k * 16 + (c - 16)];
        *(float4*)&wsm[k * 32 + c] = v;
    }
    __syncthreads();

    const float* xbase = &xsT[rg * 4];
    const float* wbase = &wsm[cg * 4];
    #pragma unroll
    for (int k = 0; k < 64; k++) {
        float4 xa = *(const float4*)&xbase[k * 132];
        float4 wa = *(const float4*)&wbase[k * 32];
        float xv[4] = {xa.x, xa.y, xa.z, xa.w};
        float wv[4] = {wa.x, wa.y, wa.z, wa.w};
        #pragma unroll
        for (int i = 0; i < 4; i++)
            #pragma unroll
            for (int j = 0; j < 4; j++) acc[i][j] += xv[i] * wv[j];
    }

    if (cg < 4) {                     // h2s cols 0..15
        int c0 = cg * 4;
        #pragma unroll
        for (int i = 0; i < 4; i++) {
            int row = r0 + rg * 4 + i;
            if (row >= n) break;
            float dv = dinv[row];
            float4 o = make_float4(acc[i][0]*dv, acc[i][1]*dv, acc[i][2]*dv, acc[i][3]*dv);
            *(float4*)&h2s[(size_t)row * 16 + c0] = o;
        }
    } else {                          // r2 cols 0..15
        int c0 = (cg - 4) * 4;
        float4 b = *(const float4*)&br2[c0];
        #pragma unroll
        for (int i = 0; i < 4; i++) {
            int row = r0 + rg * 4 + i;
            if (row >= n) break;
            float4 o = make_float4(silu_f(acc[i][0]+b.x), silu_f(acc[i][1]+b.y),
                                   silu_f(acc[i][2]+b.z), silu_f(acc[i][3]+b.w));
            *(float4*)&r2[(size_t)row * 16 + c0] = o;
        }
    }
}

// z = dinv[dst]*(sum h2s + h2s[dst]) + b2 + r2*alpha2 ; in place over r2
extern "C" __global__ __launch_bounds__(256) void k_agg2(
    const float* __restrict__ h2s, const int* __restrict__ rowstart, const int* __restrict__ deg,
    const int* __restrict__ csr, const float* __restrict__ dinv, const float* __restrict__ b2,
    const float* __restrict__ alpha2, float* __restrict__ r2z, int n)
{
    int wave = threadIdx.x >> 6, lane = threadIdx.x & 63;
    int node = blockIdx.x * 4 + wave;
    if (node >= n) return;
    int rs = rowstart[node], cnt = deg[node];
    int sub = lane >> 4, j = lane & 15;      // 4 edges per iteration, 16 feats each
    float acc = 0.0f;
    int i = sub;
    for (; i + 8 <= cnt; i += 8) {
        int sa = csr[rs + i], sb = csr[rs + i + 4];
        acc += h2s[(size_t)sa * 16 + j] + h2s[(size_t)sb * 16 + j];
    }
    for (; i < cnt; i += 4) acc += h2s[(size_t)csr[rs + i] * 16 + j];
    acc += __shfl_xor(acc, 16, 64);
    acc += __shfl_xor(acc, 32, 64);
    if (sub == 0) {
        acc += h2s[(size_t)node * 16 + j];   // self loop
        float v = dinv[node] * acc + b2[j] + r2z[(size_t)node * 16 + j] * alpha2[0];
        r2z[(size_t)node * 16 + j] = v;
    }
}

// graph mean pool: one block per graph, binary search on sorted batch
extern "C" __global__ __launch_bounds__(256) void k_pool(
    const float* __restrict__ z, const int* __restrict__ batch, float* __restrict__ emb, int n)
{
    int g = blockIdx.x;
    int lo = 0, hi = n;
    while (lo < hi) { int m = (lo + hi) >> 1; if (batch[m] < g) lo = m + 1; else hi = m; }
    int start = lo;
    lo = start; hi = n;
    while (lo < hi) { int m = (lo + hi) >> 1; if (batch[m] < g + 1) lo = m + 1; else hi = m; }
    int end = lo;
    int j = threadIdx.x & 15, grp = threadIdx.x >> 4;
    float acc = 0.0f;
    for (int r = start + grp; r < end; r += 16) acc += z[(size_t)r * 16 + j];
    __shared__ float part[16][17];
    part[grp][j] = acc;
    __syncthreads();
    if (threadIdx.x < 16) {
        float s = 0.0f;
        #pragma unroll
        for (int q = 0; q < 16; q++) s += part[q][threadIdx.x];
        float cnt = (float)(end - start);
        emb[g * 16 + threadIdx.x] = s / fmaxf(cnt, 1.0f);
    }
}

extern "C" __global__ void k_metrics(
    const float* __restrict__ tol, const float* __restrict__ cost,
    const float* __restrict__ time_, const float* __restrict__ qty,
    const float* __restrict__ mW1, const float* __restrict__ mb1,
    const float* __restrict__ mW2, const float* __restrict__ mb2,
    float* __restrict__ metrics)
{
    int t = threadIdx.x;
    if (t >= 64) return;
    int i = t >> 4, j = t & 15;
    float mv = (i == 0) ? tol[0] : (i == 1) ? cost[0] : (i == 2) ? time_[0] : qty[0];
    float acc = mb2[i * 16 + j];
    #pragma unroll
    for (int k = 0; k < 8; k++) {
        float hpre = mv * mW1[i * 8 + k] + mb1[i * 8 + k];
        acc += silu_f(hpre) * mW2[i * 128 + k * 16 + j];
    }
    metrics[t] = acc;
}

extern "C" __global__ __launch_bounds__(128) void k_head(
    const float* __restrict__ emb, const float* __restrict__ metrics,
    const float* __restrict__ Wf1, const float* __restrict__ bf1,
    const float* __restrict__ Wf2, const float* __restrict__ bf2,
    float* __restrict__ out, int NC)
{
    int g = blockIdx.x;
    __shared__ float c[80], hidden[80];
    int t = threadIdx.x;
    if (t < 16) c[t] = emb[g * 16 + t];
    else if (t < 80) c[t] = metrics[t - 16];
    __syncthreads();
    if (t < 80) {
        float acc = bf1[t];
        #pragma unroll 8
        for (int k = 0; k < 80; k++) acc += c[k] * Wf1[k * 80 + t];
        hidden[t] = silu_f(acc);
    }
    __syncthreads();
    if (t < NC) {
        float acc = bf2[t];
        #pragma unroll 8
        for (int k = 0; k < 80; k++) acc += hidden[k] * Wf2[k * NC + t];
        out[g * NC + t] = acc;
    }
}

extern "C" void kernel_launch(void* const* d_in, const int* in_sizes, int n_in,
                              void* d_out, int out_size, void* d_ws, size_t ws_size,
                              hipStream_t stream)
{
    const float* x     = (const float*)d_in[0];
    const int*   ei    = (const int*)d_in[1];
    const int*   batch = (const int*)d_in[2];
    const float* tol   = (const float*)d_in[3];
    const float* cost  = (const float*)d_in[4];
    const float* time_ = (const float*)d_in[5];
    const float* qty   = (const float*)d_in[6];
    const float* W1    = (const float*)d_in[7];
    const float* b1    = (const float*)d_in[8];
    const float* W2    = (const float*)d_in[9];
    const float* b2    = (const float*)d_in[10];
    const float* Wr1   = (const float*)d_in[11];
    const float* br1   = (const float*)d_in[12];
    const float* Wr2   = (const float*)d_in[13];
    const float* br2   = (const float*)d_in[14];
    const float* alpha1= (const float*)d_in[15];
    const float* alpha2= (const float*)d_in[16];
    const float* mW1   = (const float*)d_in[17];
    const float* mb1   = (const float*)d_in[18];
    const float* mW2   = (const float*)d_in[19];
    const float* mb2   = (const float*)d_in[20];
    const float* Wf1   = (const float*)d_in[21];
    const float* bf1   = (const float*)d_in[22];
    const float* Wf2   = (const float*)d_in[23];
    const float* bf2   = (const float*)d_in[24];

    const int N  = in_sizes[2];
    const int E  = in_sizes[1] / 2;
    const int NC = in_sizes[24];
    const int G  = out_size / NC;

    const int* srcIdx = ei;
    const int* dstIdx = ei + E;

    // bucket shift: nodes-per-bucket so nbkt <= 512 (and <= 4096 LDS cursors)
    int shift = 8;
    while (((N + (1 << shift) - 1) >> shift) > 512) shift++;
    const int nbkt = (N + (1 << shift) - 1) >> shift;

    char* w = (char*)d_ws;
    auto alloc = [&](size_t bytes) { char* p = w; w += (bytes + 255) & ~(size_t)255; return p; };
    int*   deg      = (int*)alloc((size_t)N * 4);
    int*   rowstart = (int*)alloc((size_t)N * 4);
    int*   bcount   = (int*)alloc(2048);
    int*   boff     = (int*)alloc(2052 + 252);
    int*   bcursor  = (int*)alloc(2048);
    int*   bsum     = (int*)alloc(4096);
    int*   csr      = (int*)alloc((size_t)E * 4);
    int2*  ebuf     = (int2*)alloc((size_t)E * 8);
    float* dinv     = (float*)alloc((size_t)N * 4);
    float* bufA     = (float*)alloc((size_t)N * 64 * 4);  // h0s, later h2s
    float* bufB     = (float*)alloc((size_t)N * 64 * 4);  // r1, later h (in place)
    float* bufC     = (float*)alloc((size_t)N * 16 * 4);  // r2, later z (in place)
    float* emb      = (float*)alloc((size_t)G * 16 * 4);
    float* metricsv = (float*)alloc(256);

    hipMemsetAsync(bcount, 0, 2048, stream);

    int EB8 = (E + 8191) / 8192;
    int nb  = (N + 255) / 256;
    int NB  = (N + 1023) / 1024;

    k_bhist   <<<EB8, 256, 0, stream>>>(dstIdx, bcount, E, nbkt, shift);
    k_bscan   <<<1, 512, 0, stream>>>(bcount, boff, bcursor, nbkt);
    k_bscatter<<<EB8, 256, 0, stream>>>(srcIdx, dstIdx, bcursor, ebuf, E, nbkt, shift);
    k_bdeg    <<<nbkt, 256, 0, stream>>>(ebuf, boff, deg, shift, N);
    k_dinv    <<<nb, 256, 0, stream>>>(deg, dinv, N);
    k_scan_partial<<<NB, 256, 0, stream>>>(deg, bsum, N);
    k_scan_bsum   <<<1, 64, 0, stream>>>(bsum, NB);
    k_scan_write  <<<NB, 256, 0, stream>>>(deg, bsum, rowstart, N);
    k_bfill   <<<nbkt, 256, 0, stream>>>(ebuf, boff, rowstart, csr, shift);

    k_gemm1<<<(N + 127) / 128, 256, 0, stream>>>(x, W1, Wr1, br1, dinv, bufA, bufB, N);
    k_agg1 <<<(N + 3) / 4, 256, 0, stream>>>(bufA, rowstart, deg, csr, dinv, b1, alpha1, bufB, N);
    k_gemm2<<<(N + 127) / 128, 256, 0, stream>>>(bufB, W2, Wr2, br2, dinv, bufA, bufC, N);
    k_agg2 <<<(N + 3) / 4, 256, 0, stream>>>(bufA, rowstart, deg, csr, dinv, b2, alpha2, bufC, N);
    k_pool <<<G, 256, 0, stream>>>(bufC, batch, emb, N);
    k_metrics<<<1, 64, 0, stream>>>(tol, cost, time_, qty, mW1, mb1, mW2, mb2, metricsv);
    k_head <<<G, 128, 0, stream>>>(emb, metricsv, Wf1, bf1, Wf2, bf2, (float*)d_out, NC);
}